// Round 8
// baseline (416.023 us; speedup 1.0000x reference)
//
#include <hip/hip_runtime.h>
#include <hip/hip_fp16.h>

#define HIDDEN 128
#define BSHIFT 9                  // 512 nodes per bucket
#define NBUCK_MAX 256

using f32x4 = __attribute__((ext_vector_type(4))) float;
using f16x8 = __attribute__((ext_vector_type(8))) _Float16;

// ---------------------------------------------------------------------------
// CSR build kernels
// ---------------------------------------------------------------------------
__global__ void zero_ints(int* __restrict__ a, int n) {
    int i = blockIdx.x * 256 + threadIdx.x;
    if (i < n) a[i] = 0;
}

__global__ void count_deg(const int* __restrict__ dst, int* __restrict__ deg, int e) {
    int i = blockIdx.x * 256 + threadIdx.x;
    if (i < e) atomicAdd(&deg[dst[i]], 1);
}

__global__ void scan_partial(const int* __restrict__ deg, int* __restrict__ bsum, int n) {
    __shared__ int sd[256];
    const int t = threadIdx.x;
    const int base = blockIdx.x * 1024;
    int s = 0;
    #pragma unroll
    for (int i = 0; i < 4; ++i) {
        int idx = base + t * 4 + i;
        if (idx < n) s += deg[idx];
    }
    sd[t] = s;
    __syncthreads();
    for (int o = 128; o > 0; o >>= 1) {
        if (t < o) sd[t] += sd[t + o];
        __syncthreads();
    }
    if (t == 0) bsum[blockIdx.x] = sd[0];
}

__global__ void scan_bsum(int* __restrict__ bsum, int nb) {
    __shared__ int sd[256];
    const int t = threadIdx.x;
    int v = (t < nb) ? bsum[t] : 0;
    sd[t] = v;
    __syncthreads();
    for (int o = 1; o < 256; o <<= 1) {
        int add = (t >= o) ? sd[t - o] : 0;
        __syncthreads();
        sd[t] += add;
        __syncthreads();
    }
    if (t < nb) bsum[t] = sd[t] - v;
}

__global__ void scan_offsets(const int* __restrict__ deg, const int* __restrict__ bsum,
                             int* __restrict__ offs, int n) {
    __shared__ int sd[256];
    const int t = threadIdx.x;
    const int base = blockIdx.x * 1024;
    int v[4];
    int s = 0;
    #pragma unroll
    for (int i = 0; i < 4; ++i) {
        int idx = base + t * 4 + i;
        v[i] = (idx < n) ? deg[idx] : 0;
        s += v[i];
    }
    sd[t] = s;
    __syncthreads();
    const int mine = s;
    for (int o = 1; o < 256; o <<= 1) {
        int add = (t >= o) ? sd[t - o] : 0;
        __syncthreads();
        sd[t] += add;
        __syncthreads();
    }
    int excl = sd[t] - mine + bsum[blockIdx.x];
    #pragma unroll
    for (int i = 0; i < 4; ++i) {
        int idx = base + t * 4 + i;
        if (idx < n) { offs[idx] = excl; excl += v[i]; }
    }
}

__global__ void init_cursors(const int* __restrict__ offs, int* __restrict__ cursor, int nb) {
    const int b = threadIdx.x;
    if (b < nb) cursor[b] = offs[b << BSHIFT];
}

// P1: LDS-binned partition of edges into bucket-grouped (dst,src) pairs.
__launch_bounds__(256)
__global__ void partition_pairs(const int* __restrict__ src, const int* __restrict__ dst,
                                int* __restrict__ cursor,
                                unsigned long long* __restrict__ pairs, int e) {
    __shared__ int cnt[NBUCK_MAX];
    __shared__ int base[NBUCK_MAX];
    const int t = threadIdx.x;
    const int tile0 = blockIdx.x * 4096;
    cnt[t] = 0;
    __syncthreads();
    int s[16], d[16], b[16];
    #pragma unroll
    for (int j = 0; j < 16; ++j) {
        const int i = tile0 + j * 256 + t;
        if (i < e) {
            d[j] = dst[i];
            s[j] = src[i];
            b[j] = d[j] >> BSHIFT;
            atomicAdd(&cnt[b[j]], 1);
        } else {
            b[j] = -1;
        }
    }
    __syncthreads();
    const int c = cnt[t];
    base[t] = c ? atomicAdd(&cursor[t], c) : 0;
    __syncthreads();
    cnt[t] = 0;
    __syncthreads();
    #pragma unroll
    for (int j = 0; j < 16; ++j) {
        if (b[j] >= 0) {
            const int r = atomicAdd(&cnt[b[j]], 1);
            pairs[(size_t)base[b[j]] + r] =
                ((unsigned long long)(unsigned)d[j] << 32) | (unsigned)s[j];
        }
    }
}

// P2: one block per bucket; csr writes confined to ~32KB region.
__launch_bounds__(256)
__global__ void place_csr(const unsigned long long* __restrict__ pairs,
                          const int* __restrict__ offs,
                          int* __restrict__ csr, int n, int e) {
    __shared__ int cur[1 << BSHIFT];
    const int node0 = blockIdx.x << BSHIFT;
    const int nn = min(1 << BSHIFT, n - node0);
    const int t = threadIdx.x;
    for (int i = t; i < nn; i += 256) cur[i] = offs[node0 + i];
    __syncthreads();
    const int beg = offs[node0];
    const int end = (node0 + nn < n) ? offs[node0 + nn] : e;
    for (int i = beg + t; i < end; i += 256) {
        const unsigned long long pr = pairs[i];
        const int dd = (int)(pr >> 32);
        const int ss = (int)(unsigned)pr;
        const int p = atomicAdd(&cur[dd - node0], 1);
        csr[p] = ss;
    }
}

// ---------------------------------------------------------------------------
// Pack weights into MFMA-fragment-ordered f16 planes:
//   plane0 (offset 0):      Wh  = f16(W)
//   plane1 (offset 32768):  Wls = f16((W - Wh) * 32)   [residual scaled 2^5]
// Buffer = [8 steps][8 ct][64 lane][8]; layer buffers: self steps 0-3, neigh 4-7.
// Lane l of fragment (step, ct): col = ct*16 + (l&15), k = step*32 + (l>>4)*8 + j.
// ---------------------------------------------------------------------------
__global__ void pack_weights(const float* __restrict__ W_t, const float* __restrict__ Ws0,
                             const float* __restrict__ Wn0, const float* __restrict__ Ws1,
                             const float* __restrict__ Wn1,
                             __half* p_t, __half* p_l0, __half* p_l1) {
    const int bid = blockIdx.x;
    const float* W; __half* out; int b0; int S0;
    if (bid < 16)      { W = W_t; out = p_t;  b0 = 0;  S0 = 0; }
    else if (bid < 24) { W = Ws0; out = p_l0; b0 = 16; S0 = 0; }
    else if (bid < 32) { W = Wn0; out = p_l0; b0 = 24; S0 = 4; }
    else if (bid < 40) { W = Ws1; out = p_l1; b0 = 32; S0 = 0; }
    else               { W = Wn1; out = p_l1; b0 = 40; S0 = 4; }
    const int idx = (bid - b0) * 256 + threadIdx.x;   // < K*16  (K = 256 or 128)
    const int step = idx >> 9;
    const int r = idx & 511;
    const int l = r & 63;
    const int col = (r >> 6) * 16 + (l & 15);
    const int k0 = step * 32 + ((l >> 4) << 3);
    const size_t o = (size_t)(S0 + step) * 4096 + (size_t)r * 8;
    #pragma unroll
    for (int j = 0; j < 8; ++j) {
        float f = W[(k0 + j) * HIDDEN + col];
        __half h = __float2half_rn(f);
        out[o + j] = h;
        out[32768 + o + j] = __float2half_rn((f - __half2float(h)) * 32.0f);
    }
}

// ---------------------------------------------------------------------------
// TLP GEMM (layers): one wave = 32 rows x 128 cols, K=256 ([hA|agp] fp16).
// Zero LDS, zero barriers, 3125 independent waves. A fragments loaded
// straight from global (front-loaded per K-half); W streamed from L2.
// Emulation: acc += A*Wh + (A*2^-5)*Wls.
// ---------------------------------------------------------------------------
template <bool RELU, bool FINAL>
__launch_bounds__(256, 3)
__global__ void gemm_tlp(const __half* __restrict__ A0, const __half* __restrict__ A1,
                         const __half* __restrict__ Wp,
                         const float* __restrict__ bias,
                         const float* __restrict__ wfin,
                         void* __restrict__ outv, int nrows) {
    const int t = threadIdx.x;
    const int lane = t & 63;
    const int wid = blockIdx.x * 4 + (t >> 6);
    const int row0 = wid * 32;
    if (row0 >= nrows) return;
    const int rr = lane & 15;            // row within fragment
    const int kg = lane >> 4;            // k-subgroup
    const int koff = kg << 3;
    const int r0 = min(row0 + rr, nrows - 1);
    const int r1 = min(row0 + 16 + rr, nrows - 1);

    const _Float16 S = (_Float16)0.03125f;   // 2^-5

    f32x4 acc[2][8];
    #pragma unroll
    for (int rf = 0; rf < 2; ++rf)
        #pragma unroll
        for (int c = 0; c < 8; ++c) acc[rf][c] = (f32x4){0.f, 0.f, 0.f, 0.f};

    // front-load self-half A fragments (8 independent 16B loads)
    f16x8 a0[2][4], a1[2][4];
    #pragma unroll
    for (int s = 0; s < 4; ++s) {
        a0[0][s] = *(const f16x8*)(A0 + (size_t)r0 * HIDDEN + s * 32 + koff);
        a0[1][s] = *(const f16x8*)(A0 + (size_t)r1 * HIDDEN + s * 32 + koff);
    }

    auto dostep = [&](int step, f16x8& af0, f16x8& af1) {
        const __half* wb = Wp + (size_t)step * 4096 + lane * 8;
        f16x8 as0 = af0 * S, as1 = af1 * S;
        #pragma unroll
        for (int c = 0; c < 8; ++c) {
            f16x8 wh = *(const f16x8*)(wb + c * 512);
            f16x8 wl = *(const f16x8*)(wb + 32768 + c * 512);
            acc[0][c] = __builtin_amdgcn_mfma_f32_16x16x32_f16(af0, wh, acc[0][c], 0, 0, 0);
            acc[1][c] = __builtin_amdgcn_mfma_f32_16x16x32_f16(af1, wh, acc[1][c], 0, 0, 0);
            acc[0][c] = __builtin_amdgcn_mfma_f32_16x16x32_f16(as0, wl, acc[0][c], 0, 0, 0);
            acc[1][c] = __builtin_amdgcn_mfma_f32_16x16x32_f16(as1, wl, acc[1][c], 0, 0, 0);
        }
    };

    dostep(0, a0[0][0], a0[1][0]);
    dostep(1, a0[0][1], a0[1][1]);
    // issue neigh-half A loads; steps 2-3 of self-half cover their latency
    #pragma unroll
    for (int s = 0; s < 4; ++s) {
        a1[0][s] = *(const f16x8*)(A1 + (size_t)r0 * HIDDEN + s * 32 + koff);
        a1[1][s] = *(const f16x8*)(A1 + (size_t)r1 * HIDDEN + s * 32 + koff);
    }
    dostep(2, a0[0][2], a0[1][2]);
    dostep(3, a0[0][3], a0[1][3]);
    dostep(4, a1[0][0], a1[1][0]);
    dostep(5, a1[0][1], a1[1][1]);
    dostep(6, a1[0][2], a1[1][2]);
    dostep(7, a1[0][3], a1[1][3]);

    if constexpr (FINAL) {
        // fused out = relu(acc + bias) @ wfin, pure in-wave shuffle reduction
        float wf[8], bc[8];
        #pragma unroll
        for (int c = 0; c < 8; ++c) {
            const int col = c * 16 + rr;
            wf[c] = wfin[col];
            bc[c] = bias[col];
        }
        float part[2][4];
        #pragma unroll
        for (int rf = 0; rf < 2; ++rf)
            #pragma unroll
            for (int j = 0; j < 4; ++j) {
                float s = 0.f;
                #pragma unroll
                for (int c = 0; c < 8; ++c) {
                    float v = acc[rf][c][j] + bc[c];
                    if (RELU) v = fmaxf(v, 0.f);
                    s = fmaf(v, wf[c], s);
                }
                part[rf][j] = s;
            }
        #pragma unroll
        for (int m = 1; m <= 8; m <<= 1)
            #pragma unroll
            for (int rf = 0; rf < 2; ++rf)
                #pragma unroll
                for (int j = 0; j < 4; ++j)
                    part[rf][j] += __shfl_xor(part[rf][j], m, 64);
        if (rr == 0) {
            float* out = (float*)outv;
            #pragma unroll
            for (int rf = 0; rf < 2; ++rf)
                #pragma unroll
                for (int j = 0; j < 4; ++j) {
                    const int r = row0 + rf * 16 + kg * 4 + j;
                    if (r < nrows) out[r] = part[rf][j];
                }
        }
    } else {
        __half* out = (__half*)outv;
        #pragma unroll
        for (int c = 0; c < 8; ++c) {
            const int col = c * 16 + rr;
            const float bc = bias[col];
            #pragma unroll
            for (int rf = 0; rf < 2; ++rf)
                #pragma unroll
                for (int j = 0; j < 4; ++j) {
                    const int r = row0 + rf * 16 + kg * 4 + j;
                    if (r < nrows) {
                        float v = acc[rf][c][j] + bc;
                        if (RELU) v = fmaxf(v, 0.f);
                        out[(size_t)r * HIDDEN + col] = __float2half(v);
                    }
                }
        }
    }
}

// ---------------------------------------------------------------------------
// TLP transform GEMM: x (f32, K=256) -> h0 fp16. Same wave structure; x is
// split in-register (3 products: ah*Wh + (ah*2^-5)*Wls + al*(Wh*2^-5)).
// ---------------------------------------------------------------------------
__launch_bounds__(256, 3)
__global__ void gemm_tlp_f32(const float* __restrict__ X, const __half* __restrict__ Wp,
                             const float* __restrict__ bias,
                             __half* __restrict__ outp, int nrows) {
    const int t = threadIdx.x;
    const int lane = t & 63;
    const int wid = blockIdx.x * 4 + (t >> 6);
    const int row0 = wid * 32;
    if (row0 >= nrows) return;
    const int rr = lane & 15;
    const int kg = lane >> 4;
    const int koff = kg << 3;
    const int r0 = min(row0 + rr, nrows - 1);
    const int r1 = min(row0 + 16 + rr, nrows - 1);

    const _Float16 S = (_Float16)0.03125f;

    f32x4 acc[2][8];
    #pragma unroll
    for (int rf = 0; rf < 2; ++rf)
        #pragma unroll
        for (int c = 0; c < 8; ++c) acc[rf][c] = (f32x4){0.f, 0.f, 0.f, 0.f};

    #pragma unroll
    for (int h = 0; h < 2; ++h) {
        f16x8 ah[2][4], al[2][4];
        #pragma unroll
        for (int s = 0; s < 4; ++s) {
            #pragma unroll
            for (int rf = 0; rf < 2; ++rf) {
                const float* p = X + (size_t)(rf ? r1 : r0) * 256 + (h * 4 + s) * 32 + koff;
                f32x4 x0 = *(const f32x4*)p;
                f32x4 x1 = *(const f32x4*)(p + 4);
                f16x8 hh, ll;
                #pragma unroll
                for (int j = 0; j < 4; ++j) {
                    _Float16 hv = (_Float16)x0[j];
                    hh[j] = hv;
                    ll[j] = (_Float16)((x0[j] - (float)hv) * 32.0f);
                }
                #pragma unroll
                for (int j = 0; j < 4; ++j) {
                    _Float16 hv = (_Float16)x1[j];
                    hh[4 + j] = hv;
                    ll[4 + j] = (_Float16)((x1[j] - (float)hv) * 32.0f);
                }
                ah[rf][s] = hh;
                al[rf][s] = ll;
            }
        }
        #pragma unroll
        for (int s = 0; s < 4; ++s) {
            const __half* wb = Wp + (size_t)(h * 4 + s) * 4096 + lane * 8;
            f16x8 as0 = ah[0][s] * S, as1 = ah[1][s] * S;
            #pragma unroll
            for (int c = 0; c < 8; ++c) {
                f16x8 wh = *(const f16x8*)(wb + c * 512);
                f16x8 wl = *(const f16x8*)(wb + 32768 + c * 512);
                f16x8 whs = wh * S;
                acc[0][c] = __builtin_amdgcn_mfma_f32_16x16x32_f16(ah[0][s], wh, acc[0][c], 0, 0, 0);
                acc[1][c] = __builtin_amdgcn_mfma_f32_16x16x32_f16(ah[1][s], wh, acc[1][c], 0, 0, 0);
                acc[0][c] = __builtin_amdgcn_mfma_f32_16x16x32_f16(as0, wl, acc[0][c], 0, 0, 0);
                acc[1][c] = __builtin_amdgcn_mfma_f32_16x16x32_f16(as1, wl, acc[1][c], 0, 0, 0);
                acc[0][c] = __builtin_amdgcn_mfma_f32_16x16x32_f16(al[0][s], whs, acc[0][c], 0, 0, 0);
                acc[1][c] = __builtin_amdgcn_mfma_f32_16x16x32_f16(al[1][s], whs, acc[1][c], 0, 0, 0);
            }
        }
    }

    #pragma unroll
    for (int c = 0; c < 8; ++c) {
        const int col = c * 16 + rr;
        const float bc = bias[col];
        #pragma unroll
        for (int rf = 0; rf < 2; ++rf)
            #pragma unroll
            for (int j = 0; j < 4; ++j) {
                const int r = row0 + rf * 16 + kg * 4 + j;
                if (r < nrows)
                    outp[(size_t)r * HIDDEN + col] = __float2half(acc[rf][c][j] + bc);
            }
    }
}

// ---------------------------------------------------------------------------
// Neighbor mean over fp16 h. One wave per node; 4 edge slots, each slot's
// 16 lanes load a FULL 256B row via uint4 -> 16 rows in flight per wave.
// ---------------------------------------------------------------------------
__global__ void aggregate_h16(const __half* __restrict__ h, const int* __restrict__ offs,
                              const int* __restrict__ deg, const int* __restrict__ csr,
                              __half* __restrict__ agg, int n) {
    const int node = blockIdx.x * 4 + (threadIdx.x >> 6);
    if (node >= n) return;
    const int lane = threadIdx.x & 63;
    const int slot = lane >> 4;          // edge slot (0..3)
    const int c8 = (lane & 15) * 8;      // 8 cols per lane
    const int start = offs[node];
    const int d = deg[node];
    float a[8] = {0.f, 0.f, 0.f, 0.f, 0.f, 0.f, 0.f, 0.f};
    for (int i = slot; i < d; i += 16) {
        #pragma unroll
        for (int u = 0; u < 4; ++u) {
            const int e = i + u * 4;
            if (e < d) {
                const int s = csr[start + e];
                uint4 raw = *(const uint4*)&h[(size_t)s * HIDDEN + c8];
                const __half2* hp = (const __half2*)&raw;
                #pragma unroll
                for (int m = 0; m < 4; ++m) {
                    float2 f = __half22float2(hp[m]);
                    a[2 * m] += f.x;
                    a[2 * m + 1] += f.y;
                }
            }
        }
    }
    #pragma unroll
    for (int k = 0; k < 8; ++k) {
        a[k] += __shfl_xor(a[k], 16, 64);
        a[k] += __shfl_xor(a[k], 32, 64);
    }
    if (slot == 0) {
        const float inv = 1.0f / (float)max(d, 1);
        uint4 raw;
        __half2* op = (__half2*)&raw;
        #pragma unroll
        for (int m = 0; m < 4; ++m)
            op[m] = __floats2half2_rn(a[2 * m] * inv, a[2 * m + 1] * inv);
        *(uint4*)&agg[(size_t)node * HIDDEN + c8] = raw;
    }
}

// ---------------------------------------------------------------------------
extern "C" void kernel_launch(void* const* d_in, const int* in_sizes, int n_in,
                              void* d_out, int out_size, void* d_ws, size_t ws_size,
                              hipStream_t stream) {
    const float* x     = (const float*)d_in[0];
    const float* W_t   = (const float*)d_in[1];
    const float* b_t   = (const float*)d_in[2];
    const float* W_s0  = (const float*)d_in[3];
    const float* b_s0  = (const float*)d_in[4];
    const float* W_n0  = (const float*)d_in[5];
    const float* W_s1  = (const float*)d_in[6];
    const float* b_s1  = (const float*)d_in[7];
    const float* W_n1  = (const float*)d_in[8];
    const float* W_fin = (const float*)d_in[9];
    const int*   src   = (const int*)d_in[10];
    const int*   dst   = (const int*)d_in[11];
    float* out = (float*)d_out;

    const int N = in_sizes[0] / 256;   // 100000
    const int E = in_sizes[10];        // 1600000

    size_t off_b = 0;
    auto carve = [&](size_t bytes) {
        size_t cur = off_b;
        off_b = (off_b + bytes + 255) & ~(size_t)255;
        return cur;
    };
    char* base = (char*)d_ws;
    int* deg    = (int*)(base + carve((size_t)N * 4));
    int* offs   = (int*)(base + carve((size_t)N * 4));
    int* bsum   = (int*)(base + carve(1024 * 4));
    int* cursor = (int*)(base + carve(NBUCK_MAX * 4));
    int* csr    = (int*)(base + carve((size_t)E * 4));
    unsigned long long* pairs = (unsigned long long*)(base + carve((size_t)E * 8));
    __half* wp_t  = (__half*)(base + carve((size_t)65536 * 2));
    __half* wp_l0 = (__half*)(base + carve((size_t)65536 * 2));
    __half* wp_l1 = (__half*)(base + carve((size_t)65536 * 2));
    __half* hA  = (__half*)(base + carve((size_t)N * HIDDEN * 2));
    __half* hB  = (__half*)(base + carve((size_t)N * HIDDEN * 2));
    __half* agp = (__half*)(base + carve((size_t)N * HIDDEN * 2));
    (void)ws_size; (void)n_in; (void)out_size;

    const int nbScan = (N + 1023) / 1024;
    const int nBuck  = (N + (1 << BSHIFT) - 1) >> BSHIFT;

    // --- CSR build ---
    hipLaunchKernelGGL(zero_ints, dim3((N + 255) / 256), dim3(256), 0, stream, deg, N);
    hipLaunchKernelGGL(count_deg, dim3((E + 255) / 256), dim3(256), 0, stream, dst, deg, E);
    hipLaunchKernelGGL(scan_partial, dim3(nbScan), dim3(256), 0, stream, deg, bsum, N);
    hipLaunchKernelGGL(scan_bsum, dim3(1), dim3(256), 0, stream, bsum, nbScan);
    hipLaunchKernelGGL(scan_offsets, dim3(nbScan), dim3(256), 0, stream, deg, bsum, offs, N);
    hipLaunchKernelGGL(init_cursors, dim3(1), dim3(256), 0, stream, offs, cursor, nBuck);
    hipLaunchKernelGGL(partition_pairs, dim3((E + 4095) / 4096), dim3(256), 0, stream,
                       src, dst, cursor, pairs, E);
    hipLaunchKernelGGL(place_csr, dim3(nBuck), dim3(256), 0, stream, pairs, offs, csr, N, E);

    // --- weight packing (48 tiny blocks) ---
    hipLaunchKernelGGL(pack_weights, dim3(48), dim3(256), 0, stream,
                       W_t, W_s0, W_n0, W_s1, W_n1, wp_t, wp_l0, wp_l1);

    const int nWaves = (N + 31) / 32;            // 3125
    const int gemmGrid = (nWaves + 3) / 4;       // 782
    const int nodeGrid = (N + 3) / 4;

    // h0 = x @ W_t + b_t
    hipLaunchKernelGGL(gemm_tlp_f32, dim3(gemmGrid), dim3(256), 0, stream,
                       x, wp_t, b_t, hA, N);
    // layer 0
    hipLaunchKernelGGL(aggregate_h16, dim3(nodeGrid), dim3(256), 0, stream, hA, offs, deg, csr, agp, N);
    hipLaunchKernelGGL((gemm_tlp<true, false>), dim3(gemmGrid), dim3(256), 0, stream,
                       hA, agp, wp_l0, b_s0, (const float*)nullptr, (void*)hB, N);
    // layer 1 + fused final projection
    hipLaunchKernelGGL(aggregate_h16, dim3(nodeGrid), dim3(256), 0, stream, hB, offs, deg, csr, agp, N);
    hipLaunchKernelGGL((gemm_tlp<true, true>), dim3(gemmGrid), dim3(256), 0, stream,
                       hB, agp, wp_l1, b_s1, W_fin, (void*)out, N);
}

// Round 9
// 365.917 us; speedup vs baseline: 1.1369x; 1.1369x over previous
//
#include <hip/hip_runtime.h>
#include <hip/hip_fp16.h>

#define HIDDEN 128
#define BSHIFT 9                  // 512 nodes per bucket
#define NBUCK_MAX 256

using f32x4 = __attribute__((ext_vector_type(4))) float;
using f16x8 = __attribute__((ext_vector_type(8))) _Float16;

__device__ __forceinline__ void gload16(const void* g, void* l) {
    __builtin_amdgcn_global_load_lds((const __attribute__((address_space(1))) void*)g,
                                     (__attribute__((address_space(3))) void*)l,
                                     16, 0, 0);
}

// ---------------------------------------------------------------------------
// CSR build kernels
// ---------------------------------------------------------------------------
__global__ void zero_ints(int* __restrict__ a, int n) {
    int i = blockIdx.x * 256 + threadIdx.x;
    if (i < n) a[i] = 0;
}

__global__ void count_deg(const int* __restrict__ dst, int* __restrict__ deg, int e) {
    int i = blockIdx.x * 256 + threadIdx.x;
    if (i < e) atomicAdd(&deg[dst[i]], 1);
}

__global__ void scan_partial(const int* __restrict__ deg, int* __restrict__ bsum, int n) {
    __shared__ int sd[256];
    const int t = threadIdx.x;
    const int base = blockIdx.x * 1024;
    int s = 0;
    #pragma unroll
    for (int i = 0; i < 4; ++i) {
        int idx = base + t * 4 + i;
        if (idx < n) s += deg[idx];
    }
    sd[t] = s;
    __syncthreads();
    for (int o = 128; o > 0; o >>= 1) {
        if (t < o) sd[t] += sd[t + o];
        __syncthreads();
    }
    if (t == 0) bsum[blockIdx.x] = sd[0];
}

__global__ void scan_bsum(int* __restrict__ bsum, int nb) {
    __shared__ int sd[256];
    const int t = threadIdx.x;
    int v = (t < nb) ? bsum[t] : 0;
    sd[t] = v;
    __syncthreads();
    for (int o = 1; o < 256; o <<= 1) {
        int add = (t >= o) ? sd[t - o] : 0;
        __syncthreads();
        sd[t] += add;
        __syncthreads();
    }
    if (t < nb) bsum[t] = sd[t] - v;
}

__global__ void scan_offsets(const int* __restrict__ deg, const int* __restrict__ bsum,
                             int* __restrict__ offs, int n) {
    __shared__ int sd[256];
    const int t = threadIdx.x;
    const int base = blockIdx.x * 1024;
    int v[4];
    int s = 0;
    #pragma unroll
    for (int i = 0; i < 4; ++i) {
        int idx = base + t * 4 + i;
        v[i] = (idx < n) ? deg[idx] : 0;
        s += v[i];
    }
    sd[t] = s;
    __syncthreads();
    const int mine = s;
    for (int o = 1; o < 256; o <<= 1) {
        int add = (t >= o) ? sd[t - o] : 0;
        __syncthreads();
        sd[t] += add;
        __syncthreads();
    }
    int excl = sd[t] - mine + bsum[blockIdx.x];
    #pragma unroll
    for (int i = 0; i < 4; ++i) {
        int idx = base + t * 4 + i;
        if (idx < n) { offs[idx] = excl; excl += v[i]; }
    }
}

__global__ void init_cursors(const int* __restrict__ offs, int* __restrict__ cursor, int nb) {
    const int b = threadIdx.x;
    if (b < nb) cursor[b] = offs[b << BSHIFT];
}

// P1: LDS-binned partition of edges into bucket-grouped (dst,src) pairs.
__launch_bounds__(256)
__global__ void partition_pairs(const int* __restrict__ src, const int* __restrict__ dst,
                                int* __restrict__ cursor,
                                unsigned long long* __restrict__ pairs, int e) {
    __shared__ int cnt[NBUCK_MAX];
    __shared__ int base[NBUCK_MAX];
    const int t = threadIdx.x;
    const int tile0 = blockIdx.x * 4096;
    cnt[t] = 0;
    __syncthreads();
    int s[16], d[16], b[16];
    #pragma unroll
    for (int j = 0; j < 16; ++j) {
        const int i = tile0 + j * 256 + t;
        if (i < e) {
            d[j] = dst[i];
            s[j] = src[i];
            b[j] = d[j] >> BSHIFT;
            atomicAdd(&cnt[b[j]], 1);
        } else {
            b[j] = -1;
        }
    }
    __syncthreads();
    const int c = cnt[t];
    base[t] = c ? atomicAdd(&cursor[t], c) : 0;
    __syncthreads();
    cnt[t] = 0;
    __syncthreads();
    #pragma unroll
    for (int j = 0; j < 16; ++j) {
        if (b[j] >= 0) {
            const int r = atomicAdd(&cnt[b[j]], 1);
            pairs[(size_t)base[b[j]] + r] =
                ((unsigned long long)(unsigned)d[j] << 32) | (unsigned)s[j];
        }
    }
}

// P2: one block per bucket; csr writes confined to ~32KB region.
__launch_bounds__(256)
__global__ void place_csr(const unsigned long long* __restrict__ pairs,
                          const int* __restrict__ offs,
                          int* __restrict__ csr, int n, int e) {
    __shared__ int cur[1 << BSHIFT];
    const int node0 = blockIdx.x << BSHIFT;
    const int nn = min(1 << BSHIFT, n - node0);
    const int t = threadIdx.x;
    for (int i = t; i < nn; i += 256) cur[i] = offs[node0 + i];
    __syncthreads();
    const int beg = offs[node0];
    const int end = (node0 + nn < n) ? offs[node0 + nn] : e;
    for (int i = beg + t; i < end; i += 256) {
        const unsigned long long pr = pairs[i];
        const int dd = (int)(pr >> 32);
        const int ss = (int)(unsigned)pr;
        const int p = atomicAdd(&cur[dd - node0], 1);
        csr[p] = ss;
    }
}

// ---------------------------------------------------------------------------
// Pack weights into MFMA-fragment-ordered f16 planes:
//   plane0 (offset 0):      Wh  = f16(W)
//   plane1 (offset 32768):  Wls = f16((W - Wh) * 32)   [residual scaled 2^5]
// Buffer = [8 steps][8 ct][64 lane][8]; layer buffers: self steps 0-3, neigh 4-7.
// Lane l of fragment (step, ct): col = ct*16 + (l&15), k = step*32 + (l>>4)*8 + j.
// ---------------------------------------------------------------------------
__global__ void pack_weights(const float* __restrict__ W_t, const float* __restrict__ Ws0,
                             const float* __restrict__ Wn0, const float* __restrict__ Ws1,
                             const float* __restrict__ Wn1,
                             __half* p_t, __half* p_l0, __half* p_l1) {
    const int bid = blockIdx.x;
    const float* W; __half* out; int b0; int S0;
    if (bid < 16)      { W = W_t; out = p_t;  b0 = 0;  S0 = 0; }
    else if (bid < 24) { W = Ws0; out = p_l0; b0 = 16; S0 = 0; }
    else if (bid < 32) { W = Wn0; out = p_l0; b0 = 24; S0 = 4; }
    else if (bid < 40) { W = Ws1; out = p_l1; b0 = 32; S0 = 0; }
    else               { W = Wn1; out = p_l1; b0 = 40; S0 = 4; }
    const int idx = (bid - b0) * 256 + threadIdx.x;   // < K*16  (K = 256 or 128)
    const int step = idx >> 9;
    const int r = idx & 511;
    const int l = r & 63;
    const int col = (r >> 6) * 16 + (l & 15);
    const int k0 = step * 32 + ((l >> 4) << 3);
    const size_t o = (size_t)(S0 + step) * 4096 + (size_t)r * 8;
    #pragma unroll
    for (int j = 0; j < 8; ++j) {
        float f = W[(k0 + j) * HIDDEN + col];
        __half h = __float2half_rn(f);
        out[o + j] = h;
        out[32768 + o + j] = __float2half_rn((f - __half2float(h)) * 32.0f);
    }
}

// ---------------------------------------------------------------------------
// Layer GEMM (R7 winner): A = [hA | agp] fp16 (K=128+128). Burst-stage the
// WHOLE A tile (64 KB) via global_load_lds, ONE barrier, then a barrier-free
// K-loop: ds_read_b128 fragments + L2-hot W + MFMA.
// Emulation: acc += A*Wh + (A*2^-5)*Wls. Block 128x128, 4 waves (2x2).
// ---------------------------------------------------------------------------
template <bool RELU, bool FINAL>
__launch_bounds__(256, 2)
__global__ void gemm_h16(const __half* __restrict__ A0, const __half* __restrict__ A1,
                         const __half* __restrict__ Wp,
                         const float* __restrict__ bias,
                         const float* __restrict__ wfin,
                         void* __restrict__ outv, int nrows) {
    __shared__ __align__(16) __half As[8][8][64][8];   // [step][rt][lane][8] = 64 KB

    const int t = threadIdx.x;
    const int lane = t & 63;
    const int w = t >> 6;
    const int wr = w >> 1, wc = w & 1;
    const int blockRow0 = blockIdx.x * 128;
    const int koff = (lane >> 4) << 3;

    // burst-stage: wave w stages rt = 2w, 2w+1 for all 8 steps (16 DMA ops in flight)
    #pragma unroll
    for (int i = 0; i < 2; ++i) {
        const int rt = w * 2 + i;
        const int row = min(blockRow0 + rt * 16 + (lane & 15), nrows - 1);
        #pragma unroll
        for (int step = 0; step < 8; ++step) {
            const __half* src = ((step < 4) ? A0 : A1) + (size_t)row * HIDDEN + (step & 3) * 32 + koff;
            gload16(src, &As[step][rt][0][0]);
        }
    }
    __syncthreads();   // single drain; LDS read-only afterwards

    f32x4 acc[4][4];
    #pragma unroll
    for (int i = 0; i < 4; ++i)
        #pragma unroll
        for (int j = 0; j < 4; ++j) acc[i][j] = (f32x4){0.f, 0.f, 0.f, 0.f};

    const _Float16 S = (_Float16)0.03125f;   // 2^-5

    #pragma unroll
    for (int step = 0; step < 8; ++step) {
        const __half* wb = Wp + (size_t)step * 4096 + (wc * 4) * 512 + lane * 8;
        f16x8 wh[4], wl[4];
        #pragma unroll
        for (int c4 = 0; c4 < 4; ++c4) {
            wh[c4] = *(const f16x8*)(wb + c4 * 512);
            wl[c4] = *(const f16x8*)(wb + 32768 + c4 * 512);
        }
        f16x8 a[4], asr[4];
        #pragma unroll
        for (int r4 = 0; r4 < 4; ++r4) {
            a[r4] = *(const f16x8*)&As[step][wr * 4 + r4][lane][0];
            asr[r4] = a[r4] * S;
        }
        #pragma unroll
        for (int r4 = 0; r4 < 4; ++r4)
            #pragma unroll
            for (int c4 = 0; c4 < 4; ++c4) {
                acc[r4][c4] = __builtin_amdgcn_mfma_f32_16x16x32_f16(a[r4], wh[c4], acc[r4][c4], 0, 0, 0);
                acc[r4][c4] = __builtin_amdgcn_mfma_f32_16x16x32_f16(asr[r4], wl[c4], acc[r4][c4], 0, 0, 0);
            }
    }

    // epilogue
    if constexpr (FINAL) {
        __shared__ float red[128][2];
        float wf[4], bc[4];
        #pragma unroll
        for (int c4 = 0; c4 < 4; ++c4) {
            const int col = (wc * 4 + c4) * 16 + (lane & 15);
            wf[c4] = wfin[col];
            bc[c4] = bias[col];
        }
        float part[4][4];
        #pragma unroll
        for (int r4 = 0; r4 < 4; ++r4)
            #pragma unroll
            for (int j = 0; j < 4; ++j) {
                float s = 0.f;
                #pragma unroll
                for (int c4 = 0; c4 < 4; ++c4) {
                    float v = acc[r4][c4][j] + bc[c4];
                    if (RELU) v = fmaxf(v, 0.f);
                    s = fmaf(v, wf[c4], s);
                }
                part[r4][j] = s;
            }
        #pragma unroll
        for (int o = 1; o < 16; o <<= 1)
            #pragma unroll
            for (int r4 = 0; r4 < 4; ++r4)
                #pragma unroll
                for (int j = 0; j < 4; ++j)
                    part[r4][j] += __shfl_xor(part[r4][j], o, 64);
        if ((lane & 15) == 0) {
            #pragma unroll
            for (int r4 = 0; r4 < 4; ++r4)
                #pragma unroll
                for (int j = 0; j < 4; ++j) {
                    const int rl = wr * 64 + r4 * 16 + ((lane >> 4) << 2) + j;
                    red[rl][wc] = part[r4][j];
                }
        }
        __syncthreads();
        if (t < 128) {
            const int r = blockRow0 + t;
            if (r < nrows) ((float*)outv)[r] = red[t][0] + red[t][1];
        }
    } else {
        __half* out = (__half*)outv;
        #pragma unroll
        for (int c4 = 0; c4 < 4; ++c4) {
            const int col = (wc * 4 + c4) * 16 + (lane & 15);
            const float bc = bias[col];
            #pragma unroll
            for (int r4 = 0; r4 < 4; ++r4) {
                const int r0 = blockRow0 + (wr * 4 + r4) * 16 + ((lane >> 4) << 2);
                #pragma unroll
                for (int j = 0; j < 4; ++j) {
                    const int r = r0 + j;
                    if (r < nrows) {
                        float v = acc[r4][c4][j] + bc;
                        if (RELU) v = fmaxf(v, 0.f);
                        out[(size_t)r * HIDDEN + col] = __float2half(v);
                    }
                }
            }
        }
    }
}

// ---------------------------------------------------------------------------
// Transform GEMM: x (f32, K=256) cast to fp16 DURING reg-staging (residual
// dropped: x fp16-cast error ~2.8e-4 rel, same scale as fp16 h storage).
// Stage: 32 independent float4 loads/thread -> cvt -> ds_write; ONE barrier;
// then the identical 2-product K-loop as gemm_h16.
// ---------------------------------------------------------------------------
__launch_bounds__(256, 2)
__global__ void gemm_x16(const float* __restrict__ X, const __half* __restrict__ Wp,
                         const float* __restrict__ bias,
                         __half* __restrict__ outp, int nrows) {
    __shared__ __align__(16) __half As[8][8][64][8];   // 64 KB

    const int t = threadIdx.x;
    const int lane = t & 63;
    const int w = t >> 6;
    const int wr = w >> 1, wc = w & 1;
    const int blockRow0 = blockIdx.x * 128;
    const int koff = (lane >> 4) << 3;

    // reg-stage + cast: wave w covers rt = 2w, 2w+1, all 8 steps
    #pragma unroll
    for (int i = 0; i < 2; ++i) {
        const int rt = w * 2 + i;
        const int row = min(blockRow0 + rt * 16 + (lane & 15), nrows - 1);
        #pragma unroll
        for (int step = 0; step < 8; ++step) {
            const float* p = X + (size_t)row * 256 + step * 32 + koff;
            f32x4 x0 = *(const f32x4*)p;
            f32x4 x1 = *(const f32x4*)(p + 4);
            f16x8 hh;
            #pragma unroll
            for (int j = 0; j < 4; ++j) hh[j] = (_Float16)x0[j];
            #pragma unroll
            for (int j = 0; j < 4; ++j) hh[4 + j] = (_Float16)x1[j];
            *(f16x8*)&As[step][rt][lane][0] = hh;
        }
    }
    __syncthreads();

    f32x4 acc[4][4];
    #pragma unroll
    for (int i = 0; i < 4; ++i)
        #pragma unroll
        for (int j = 0; j < 4; ++j) acc[i][j] = (f32x4){0.f, 0.f, 0.f, 0.f};

    const _Float16 S = (_Float16)0.03125f;   // 2^-5

    #pragma unroll
    for (int step = 0; step < 8; ++step) {
        const __half* wb = Wp + (size_t)step * 4096 + (wc * 4) * 512 + lane * 8;
        f16x8 wh[4], wl[4];
        #pragma unroll
        for (int c4 = 0; c4 < 4; ++c4) {
            wh[c4] = *(const f16x8*)(wb + c4 * 512);
            wl[c4] = *(const f16x8*)(wb + 32768 + c4 * 512);
        }
        f16x8 a[4], asr[4];
        #pragma unroll
        for (int r4 = 0; r4 < 4; ++r4) {
            a[r4] = *(const f16x8*)&As[step][wr * 4 + r4][lane][0];
            asr[r4] = a[r4] * S;
        }
        #pragma unroll
        for (int r4 = 0; r4 < 4; ++r4)
            #pragma unroll
            for (int c4 = 0; c4 < 4; ++c4) {
                acc[r4][c4] = __builtin_amdgcn_mfma_f32_16x16x32_f16(a[r4], wh[c4], acc[r4][c4], 0, 0, 0);
                acc[r4][c4] = __builtin_amdgcn_mfma_f32_16x16x32_f16(asr[r4], wl[c4], acc[r4][c4], 0, 0, 0);
            }
    }

    // epilogue: bias, fp16 h store
    #pragma unroll
    for (int c4 = 0; c4 < 4; ++c4) {
        const int col = (wc * 4 + c4) * 16 + (lane & 15);
        const float bc = bias[col];
        #pragma unroll
        for (int r4 = 0; r4 < 4; ++r4) {
            const int r0 = blockRow0 + (wr * 4 + r4) * 16 + ((lane >> 4) << 2);
            #pragma unroll
            for (int j = 0; j < 4; ++j) {
                const int r = r0 + j;
                if (r < nrows)
                    outp[(size_t)r * HIDDEN + col] = __float2half(acc[r4][c4][j] + bc);
            }
        }
    }
}

// ---------------------------------------------------------------------------
// Neighbor mean over fp16 h. One wave per node; 4 edge slots, each slot's
// 16 lanes load a FULL 256B row via uint4 -> 16 rows in flight per wave.
// ---------------------------------------------------------------------------
__global__ void aggregate_h16(const __half* __restrict__ h, const int* __restrict__ offs,
                              const int* __restrict__ deg, const int* __restrict__ csr,
                              __half* __restrict__ agg, int n) {
    const int node = blockIdx.x * 4 + (threadIdx.x >> 6);
    if (node >= n) return;
    const int lane = threadIdx.x & 63;
    const int slot = lane >> 4;          // edge slot (0..3)
    const int c8 = (lane & 15) * 8;      // 8 cols per lane
    const int start = offs[node];
    const int d = deg[node];
    float a[8] = {0.f, 0.f, 0.f, 0.f, 0.f, 0.f, 0.f, 0.f};
    for (int i = slot; i < d; i += 16) {
        #pragma unroll
        for (int u = 0; u < 4; ++u) {
            const int e = i + u * 4;
            if (e < d) {
                const int s = csr[start + e];
                uint4 raw = *(const uint4*)&h[(size_t)s * HIDDEN + c8];
                const __half2* hp = (const __half2*)&raw;
                #pragma unroll
                for (int m = 0; m < 4; ++m) {
                    float2 f = __half22float2(hp[m]);
                    a[2 * m] += f.x;
                    a[2 * m + 1] += f.y;
                }
            }
        }
    }
    #pragma unroll
    for (int k = 0; k < 8; ++k) {
        a[k] += __shfl_xor(a[k], 16, 64);
        a[k] += __shfl_xor(a[k], 32, 64);
    }
    if (slot == 0) {
        const float inv = 1.0f / (float)max(d, 1);
        uint4 raw;
        __half2* op = (__half2*)&raw;
        #pragma unroll
        for (int m = 0; m < 4; ++m)
            op[m] = __floats2half2_rn(a[2 * m] * inv, a[2 * m + 1] * inv);
        *(uint4*)&agg[(size_t)node * HIDDEN + c8] = raw;
    }
}

// ---------------------------------------------------------------------------
extern "C" void kernel_launch(void* const* d_in, const int* in_sizes, int n_in,
                              void* d_out, int out_size, void* d_ws, size_t ws_size,
                              hipStream_t stream) {
    const float* x     = (const float*)d_in[0];
    const float* W_t   = (const float*)d_in[1];
    const float* b_t   = (const float*)d_in[2];
    const float* W_s0  = (const float*)d_in[3];
    const float* b_s0  = (const float*)d_in[4];
    const float* W_n0  = (const float*)d_in[5];
    const float* W_s1  = (const float*)d_in[6];
    const float* b_s1  = (const float*)d_in[7];
    const float* W_n1  = (const float*)d_in[8];
    const float* W_fin = (const float*)d_in[9];
    const int*   src   = (const int*)d_in[10];
    const int*   dst   = (const int*)d_in[11];
    float* out = (float*)d_out;

    const int N = in_sizes[0] / 256;   // 100000
    const int E = in_sizes[10];        // 1600000

    size_t off_b = 0;
    auto carve = [&](size_t bytes) {
        size_t cur = off_b;
        off_b = (off_b + bytes + 255) & ~(size_t)255;
        return cur;
    };
    char* base = (char*)d_ws;
    int* deg    = (int*)(base + carve((size_t)N * 4));
    int* offs   = (int*)(base + carve((size_t)N * 4));
    int* bsum   = (int*)(base + carve(1024 * 4));
    int* cursor = (int*)(base + carve(NBUCK_MAX * 4));
    int* csr    = (int*)(base + carve((size_t)E * 4));
    unsigned long long* pairs = (unsigned long long*)(base + carve((size_t)E * 8));
    __half* wp_t  = (__half*)(base + carve((size_t)65536 * 2));
    __half* wp_l0 = (__half*)(base + carve((size_t)65536 * 2));
    __half* wp_l1 = (__half*)(base + carve((size_t)65536 * 2));
    __half* hA  = (__half*)(base + carve((size_t)N * HIDDEN * 2));
    __half* hB  = (__half*)(base + carve((size_t)N * HIDDEN * 2));
    __half* agp = (__half*)(base + carve((size_t)N * HIDDEN * 2));
    (void)ws_size; (void)n_in; (void)out_size;

    const int nbScan = (N + 1023) / 1024;
    const int nBuck  = (N + (1 << BSHIFT) - 1) >> BSHIFT;

    // --- CSR build ---
    hipLaunchKernelGGL(zero_ints, dim3((N + 255) / 256), dim3(256), 0, stream, deg, N);
    hipLaunchKernelGGL(count_deg, dim3((E + 255) / 256), dim3(256), 0, stream, dst, deg, E);
    hipLaunchKernelGGL(scan_partial, dim3(nbScan), dim3(256), 0, stream, deg, bsum, N);
    hipLaunchKernelGGL(scan_bsum, dim3(1), dim3(256), 0, stream, bsum, nbScan);
    hipLaunchKernelGGL(scan_offsets, dim3(nbScan), dim3(256), 0, stream, deg, bsum, offs, N);
    hipLaunchKernelGGL(init_cursors, dim3(1), dim3(256), 0, stream, offs, cursor, nBuck);
    hipLaunchKernelGGL(partition_pairs, dim3((E + 4095) / 4096), dim3(256), 0, stream,
                       src, dst, cursor, pairs, E);
    hipLaunchKernelGGL(place_csr, dim3(nBuck), dim3(256), 0, stream, pairs, offs, csr, N, E);

    // --- weight packing (48 tiny blocks) ---
    hipLaunchKernelGGL(pack_weights, dim3(48), dim3(256), 0, stream,
                       W_t, W_s0, W_n0, W_s1, W_n1, wp_t, wp_l0, wp_l1);

    const int gemmGrid = (N + 127) / 128;
    const int nodeGrid = (N + 3) / 4;

    // h0 = x @ W_t + b_t  (x cast to fp16 at staging)
    hipLaunchKernelGGL(gemm_x16, dim3(gemmGrid), dim3(256), 0, stream,
                       x, wp_t, b_t, hA, N);
    // layer 0
    hipLaunchKernelGGL(aggregate_h16, dim3(nodeGrid), dim3(256), 0, stream, hA, offs, deg, csr, agp, N);
    hipLaunchKernelGGL((gemm_h16<true, false>), dim3(gemmGrid), dim3(256), 0, stream,
                       hA, agp, wp_l0, b_s0, (const float*)nullptr, (void*)hB, N);
    // layer 1 + fused final projection
    hipLaunchKernelGGL(aggregate_h16, dim3(nodeGrid), dim3(256), 0, stream, hB, offs, deg, csr, agp, N);
    hipLaunchKernelGGL((gemm_h16<true, true>), dim3(gemmGrid), dim3(256), 0, stream,
                       hB, agp, wp_l1, b_s1, W_fin, (void*)out, N);
}

// Round 10
// 307.327 us; speedup vs baseline: 1.3537x; 1.1906x over previous
//
#include <hip/hip_runtime.h>
#include <hip/hip_fp16.h>

#define HIDDEN 128
#define BSHIFT 9                  // 512 nodes per bucket
#define NBUCK_MAX 256

using f32x4 = __attribute__((ext_vector_type(4))) float;
using f16x8 = __attribute__((ext_vector_type(8))) _Float16;

__device__ __forceinline__ void gload16(const void* g, void* l) {
    __builtin_amdgcn_global_load_lds((const __attribute__((address_space(1))) void*)g,
                                     (__attribute__((address_space(3))) void*)l,
                                     16, 0, 0);
}

// ---------------------------------------------------------------------------
// CSR build (bucketed, no per-node global atomics)
// ---------------------------------------------------------------------------
__global__ void zero_ints(int* __restrict__ a, int n) {
    int i = blockIdx.x * 256 + threadIdx.x;
    if (i < n) a[i] = 0;
}

// Per-bucket histogram of dst>>BSHIFT via LDS binning.
__launch_bounds__(256)
__global__ void bucket_hist(const int* __restrict__ dst, int* __restrict__ bcnt, int e) {
    __shared__ int c[NBUCK_MAX];
    const int t = threadIdx.x;
    c[t] = 0;
    __syncthreads();
    const int tile0 = blockIdx.x * 4096;
    const int end = min(e, tile0 + 4096);
    for (int i = tile0 + t; i < end; i += 256)
        atomicAdd(&c[dst[i] >> BSHIFT], 1);
    __syncthreads();
    if (c[t]) atomicAdd(&bcnt[t], c[t]);
}

// Exclusive scan of bucket counts (nb <= 256), writes boffs[0..nb] and cursor.
__global__ void scan_buckets(const int* __restrict__ bcnt, int* __restrict__ boffs,
                             int* __restrict__ cursor, int nb) {
    __shared__ int sd[256];
    const int t = threadIdx.x;
    int v = (t < nb) ? bcnt[t] : 0;
    sd[t] = v;
    __syncthreads();
    for (int o = 1; o < 256; o <<= 1) {
        int add = (t >= o) ? sd[t - o] : 0;
        __syncthreads();
        sd[t] += add;
        __syncthreads();
    }
    const int ex = sd[t] - v;
    if (t < nb) { boffs[t] = ex; cursor[t] = ex; }
    if (t == nb - 1) boffs[nb] = ex + v;
}

// P1: LDS-binned partition of edges into bucket-grouped (dst,src) pairs.
__launch_bounds__(256)
__global__ void partition_pairs(const int* __restrict__ src, const int* __restrict__ dst,
                                int* __restrict__ cursor,
                                unsigned long long* __restrict__ pairs, int e) {
    __shared__ int cnt[NBUCK_MAX];
    __shared__ int base[NBUCK_MAX];
    const int t = threadIdx.x;
    const int tile0 = blockIdx.x * 4096;
    cnt[t] = 0;
    __syncthreads();
    int s[16], d[16], b[16];
    #pragma unroll
    for (int j = 0; j < 16; ++j) {
        const int i = tile0 + j * 256 + t;
        if (i < e) {
            d[j] = dst[i];
            s[j] = src[i];
            b[j] = d[j] >> BSHIFT;
            atomicAdd(&cnt[b[j]], 1);
        } else {
            b[j] = -1;
        }
    }
    __syncthreads();
    const int c = cnt[t];
    base[t] = c ? atomicAdd(&cursor[t], c) : 0;
    __syncthreads();
    cnt[t] = 0;
    __syncthreads();
    #pragma unroll
    for (int j = 0; j < 16; ++j) {
        if (b[j] >= 0) {
            const int r = atomicAdd(&cnt[b[j]], 1);
            pairs[(size_t)base[b[j]] + r] =
                ((unsigned long long)(unsigned)d[j] << 32) | (unsigned)s[j];
        }
    }
}

// P2: one block per bucket. Pass 1: LDS per-node counts + LDS scan -> offs.
// Pass 2: place csr within the bucket's region (L2-local writes).
__launch_bounds__(256)
__global__ void place_csr2(const unsigned long long* __restrict__ pairs,
                           const int* __restrict__ boffs,
                           int* __restrict__ offs, int* __restrict__ csr,
                           int n, int e) {
    __shared__ int cnt[1 << BSHIFT];
    __shared__ int sc[256];
    const int b = blockIdx.x;
    const int t = threadIdx.x;
    const int node0 = b << BSHIFT;
    const int nn = min(1 << BSHIFT, n - node0);
    cnt[t] = 0;
    cnt[t + 256] = 0;
    __syncthreads();
    const int beg = boffs[b], end = boffs[b + 1];
    for (int i = beg + t; i < end; i += 256)
        atomicAdd(&cnt[(int)(pairs[i] >> 32) - node0], 1);
    __syncthreads();
    const int a0 = cnt[2 * t], a1 = cnt[2 * t + 1];
    const int s = a0 + a1;
    sc[t] = s;
    __syncthreads();
    for (int o = 1; o < 256; o <<= 1) {
        int add = (t >= o) ? sc[t - o] : 0;
        __syncthreads();
        sc[t] += add;
        __syncthreads();
    }
    const int g0 = beg + sc[t] - s;
    const int g1 = g0 + a0;
    if (2 * t < nn)     offs[node0 + 2 * t] = g0;
    if (2 * t + 1 < nn) offs[node0 + 2 * t + 1] = g1;
    __syncthreads();
    cnt[2 * t] = g0;
    cnt[2 * t + 1] = g1;
    if (node0 + nn == n && t == 0) offs[n] = e;   // sentinel
    __syncthreads();
    for (int i = beg + t; i < end; i += 256) {
        const unsigned long long pr = pairs[i];
        const int dd = (int)(pr >> 32) - node0;
        const int ss = (int)(unsigned)pr;
        const int p = atomicAdd(&cnt[dd], 1);
        csr[p] = ss;
    }
}

// ---------------------------------------------------------------------------
// Pack weights into MFMA-fragment-ordered f16 planes:
//   plane0 (offset 0):      Wh  = f16(W)
//   plane1 (offset 32768):  Wls = f16((W - Wh) * 32)   [residual scaled 2^5]
// Buffer = [8 steps][8 ct][64 lane][8]; layer buffers: self steps 0-3, neigh 4-7.
// Lane l of fragment (step, ct): col = ct*16 + (l&15), k = step*32 + (l>>4)*8 + j.
// ---------------------------------------------------------------------------
__global__ void pack_weights(const float* __restrict__ W_t, const float* __restrict__ Ws0,
                             const float* __restrict__ Wn0, const float* __restrict__ Ws1,
                             const float* __restrict__ Wn1,
                             __half* p_t, __half* p_l0, __half* p_l1) {
    const int bid = blockIdx.x;
    const float* W; __half* out; int b0; int S0;
    if (bid < 16)      { W = W_t; out = p_t;  b0 = 0;  S0 = 0; }
    else if (bid < 24) { W = Ws0; out = p_l0; b0 = 16; S0 = 0; }
    else if (bid < 32) { W = Wn0; out = p_l0; b0 = 24; S0 = 4; }
    else if (bid < 40) { W = Ws1; out = p_l1; b0 = 32; S0 = 0; }
    else               { W = Wn1; out = p_l1; b0 = 40; S0 = 4; }
    const int idx = (bid - b0) * 256 + threadIdx.x;   // < K*16  (K = 256 or 128)
    const int step = idx >> 9;
    const int r = idx & 511;
    const int l = r & 63;
    const int col = (r >> 6) * 16 + (l & 15);
    const int k0 = step * 32 + ((l >> 4) << 3);
    const size_t o = (size_t)(S0 + step) * 4096 + (size_t)r * 8;
    #pragma unroll
    for (int j = 0; j < 8; ++j) {
        float f = W[(k0 + j) * HIDDEN + col];
        __half h = __float2half_rn(f);
        out[o + j] = h;
        out[32768 + o + j] = __float2half_rn((f - __half2float(h)) * 32.0f);
    }
}

// ---------------------------------------------------------------------------
// Layer GEMM (R7 winner): A = [hA | agp] fp16 (K=128+128). Burst-stage the
// WHOLE A tile (64 KB) via global_load_lds, ONE barrier, then a barrier-free
// K-loop: ds_read_b128 fragments + L2-hot W + MFMA.
// Emulation: acc += A*Wh + (A*2^-5)*Wls. Block 128x128, 4 waves (2x2).
// ---------------------------------------------------------------------------
template <bool RELU, bool FINAL>
__launch_bounds__(256, 2)
__global__ void gemm_h16(const __half* __restrict__ A0, const __half* __restrict__ A1,
                         const __half* __restrict__ Wp,
                         const float* __restrict__ bias,
                         const float* __restrict__ wfin,
                         void* __restrict__ outv, int nrows) {
    __shared__ __align__(16) __half As[8][8][64][8];   // [step][rt][lane][8] = 64 KB

    const int t = threadIdx.x;
    const int lane = t & 63;
    const int w = t >> 6;
    const int wr = w >> 1, wc = w & 1;
    const int blockRow0 = blockIdx.x * 128;
    const int koff = (lane >> 4) << 3;

    // burst-stage: wave w stages rt = 2w, 2w+1 for all 8 steps (16 DMA ops in flight)
    #pragma unroll
    for (int i = 0; i < 2; ++i) {
        const int rt = w * 2 + i;
        const int row = min(blockRow0 + rt * 16 + (lane & 15), nrows - 1);
        #pragma unroll
        for (int step = 0; step < 8; ++step) {
            const __half* src = ((step < 4) ? A0 : A1) + (size_t)row * HIDDEN + (step & 3) * 32 + koff;
            gload16(src, &As[step][rt][0][0]);
        }
    }
    __syncthreads();   // single drain; LDS read-only afterwards

    f32x4 acc[4][4];
    #pragma unroll
    for (int i = 0; i < 4; ++i)
        #pragma unroll
        for (int j = 0; j < 4; ++j) acc[i][j] = (f32x4){0.f, 0.f, 0.f, 0.f};

    const _Float16 S = (_Float16)0.03125f;   // 2^-5

    #pragma unroll
    for (int step = 0; step < 8; ++step) {
        const __half* wb = Wp + (size_t)step * 4096 + (wc * 4) * 512 + lane * 8;
        f16x8 wh[4], wl[4];
        #pragma unroll
        for (int c4 = 0; c4 < 4; ++c4) {
            wh[c4] = *(const f16x8*)(wb + c4 * 512);
            wl[c4] = *(const f16x8*)(wb + 32768 + c4 * 512);
        }
        f16x8 a[4], asr[4];
        #pragma unroll
        for (int r4 = 0; r4 < 4; ++r4) {
            a[r4] = *(const f16x8*)&As[step][wr * 4 + r4][lane][0];
            asr[r4] = a[r4] * S;
        }
        #pragma unroll
        for (int r4 = 0; r4 < 4; ++r4)
            #pragma unroll
            for (int c4 = 0; c4 < 4; ++c4) {
                acc[r4][c4] = __builtin_amdgcn_mfma_f32_16x16x32_f16(a[r4], wh[c4], acc[r4][c4], 0, 0, 0);
                acc[r4][c4] = __builtin_amdgcn_mfma_f32_16x16x32_f16(asr[r4], wl[c4], acc[r4][c4], 0, 0, 0);
            }
    }

    // epilogue
    if constexpr (FINAL) {
        __shared__ float red[128][2];
        float wf[4], bc[4];
        #pragma unroll
        for (int c4 = 0; c4 < 4; ++c4) {
            const int col = (wc * 4 + c4) * 16 + (lane & 15);
            wf[c4] = wfin[col];
            bc[c4] = bias[col];
        }
        float part[4][4];
        #pragma unroll
        for (int r4 = 0; r4 < 4; ++r4)
            #pragma unroll
            for (int j = 0; j < 4; ++j) {
                float s = 0.f;
                #pragma unroll
                for (int c4 = 0; c4 < 4; ++c4) {
                    float v = acc[r4][c4][j] + bc[c4];
                    if (RELU) v = fmaxf(v, 0.f);
                    s = fmaf(v, wf[c4], s);
                }
                part[r4][j] = s;
            }
        #pragma unroll
        for (int o = 1; o < 16; o <<= 1)
            #pragma unroll
            for (int r4 = 0; r4 < 4; ++r4)
                #pragma unroll
                for (int j = 0; j < 4; ++j)
                    part[r4][j] += __shfl_xor(part[r4][j], o, 64);
        if ((lane & 15) == 0) {
            #pragma unroll
            for (int r4 = 0; r4 < 4; ++r4)
                #pragma unroll
                for (int j = 0; j < 4; ++j) {
                    const int rl = wr * 64 + r4 * 16 + ((lane >> 4) << 2) + j;
                    red[rl][wc] = part[r4][j];
                }
        }
        __syncthreads();
        if (t < 128) {
            const int r = blockRow0 + t;
            if (r < nrows) ((float*)outv)[r] = red[t][0] + red[t][1];
        }
    } else {
        __half* out = (__half*)outv;
        #pragma unroll
        for (int c4 = 0; c4 < 4; ++c4) {
            const int col = (wc * 4 + c4) * 16 + (lane & 15);
            const float bc = bias[col];
            #pragma unroll
            for (int r4 = 0; r4 < 4; ++r4) {
                const int r0 = blockRow0 + (wr * 4 + r4) * 16 + ((lane >> 4) << 2);
                #pragma unroll
                for (int j = 0; j < 4; ++j) {
                    const int r = r0 + j;
                    if (r < nrows) {
                        float v = acc[r4][c4][j] + bc;
                        if (RELU) v = fmaxf(v, 0.f);
                        out[(size_t)r * HIDDEN + col] = __float2half(v);
                    }
                }
            }
        }
    }
}

// ---------------------------------------------------------------------------
// Transform GEMM: x (f32, K=256). 64-row tile -> the f32 A tile is 64 KB,
// single global_load_lds burst + ONE barrier (same structure as gemm_h16).
// f32 -> f16 conversion happens at fragment-read time in the K-loop.
// Block 64x128, 4 waves (2x2), wave tile 32x64.
// LDS: Xs[step][rt][half][lane][4 f32]; lane l of (step,rt) holds
// row = rt*16 + (l&15), k = step*32 + (l>>4)*8 (+4 for half 1).
// ---------------------------------------------------------------------------
__launch_bounds__(256, 2)
__global__ void gemm_x32(const float* __restrict__ X, const __half* __restrict__ Wp,
                         const float* __restrict__ bias,
                         __half* __restrict__ outp, int nrows) {
    __shared__ __align__(16) float Xs[8][4][2][64][4];   // 64 KB

    const int t = threadIdx.x;
    const int lane = t & 63;
    const int w = t >> 6;
    const int wr = w >> 1, wc = w & 1;
    const int blockRow0 = blockIdx.x * 64;
    const int koff = (lane >> 4) << 3;

    // burst-stage: wave w stages rt = w for all 8 steps x 2 halves (16 DMAs)
    {
        const int rt = w;
        const int row = min(blockRow0 + rt * 16 + (lane & 15), nrows - 1);
        #pragma unroll
        for (int step = 0; step < 8; ++step) {
            const float* src = X + (size_t)row * 256 + step * 32 + koff;
            gload16(src,     &Xs[step][rt][0][0][0]);
            gload16(src + 4, &Xs[step][rt][1][0][0]);
        }
    }
    __syncthreads();   // single drain

    f32x4 acc[2][4];
    #pragma unroll
    for (int i = 0; i < 2; ++i)
        #pragma unroll
        for (int j = 0; j < 4; ++j) acc[i][j] = (f32x4){0.f, 0.f, 0.f, 0.f};

    const _Float16 S = (_Float16)0.03125f;   // 2^-5

    #pragma unroll
    for (int step = 0; step < 8; ++step) {
        const __half* wb = Wp + (size_t)step * 4096 + (wc * 4) * 512 + lane * 8;
        f16x8 wh[4], wl[4];
        #pragma unroll
        for (int c4 = 0; c4 < 4; ++c4) {
            wh[c4] = *(const f16x8*)(wb + c4 * 512);
            wl[c4] = *(const f16x8*)(wb + 32768 + c4 * 512);
        }
        f16x8 a[2], asr[2];
        #pragma unroll
        for (int r4 = 0; r4 < 2; ++r4) {
            const int rt = wr * 2 + r4;
            f32x4 x0 = *(const f32x4*)&Xs[step][rt][0][lane][0];
            f32x4 x1 = *(const f32x4*)&Xs[step][rt][1][lane][0];
            f16x8 hh;
            #pragma unroll
            for (int j = 0; j < 4; ++j) hh[j] = (_Float16)x0[j];
            #pragma unroll
            for (int j = 0; j < 4; ++j) hh[4 + j] = (_Float16)x1[j];
            a[r4] = hh;
            asr[r4] = hh * S;
        }
        #pragma unroll
        for (int r4 = 0; r4 < 2; ++r4)
            #pragma unroll
            for (int c4 = 0; c4 < 4; ++c4) {
                acc[r4][c4] = __builtin_amdgcn_mfma_f32_16x16x32_f16(a[r4], wh[c4], acc[r4][c4], 0, 0, 0);
                acc[r4][c4] = __builtin_amdgcn_mfma_f32_16x16x32_f16(asr[r4], wl[c4], acc[r4][c4], 0, 0, 0);
            }
    }

    // epilogue: bias, fp16 h store
    #pragma unroll
    for (int c4 = 0; c4 < 4; ++c4) {
        const int col = (wc * 4 + c4) * 16 + (lane & 15);
        const float bc = bias[col];
        #pragma unroll
        for (int r4 = 0; r4 < 2; ++r4) {
            const int r0 = blockRow0 + (wr * 2 + r4) * 16 + ((lane >> 4) << 2);
            #pragma unroll
            for (int j = 0; j < 4; ++j) {
                const int r = r0 + j;
                if (r < nrows)
                    outp[(size_t)r * HIDDEN + col] = __float2half(acc[r4][c4][j] + bc);
            }
        }
    }
}

// ---------------------------------------------------------------------------
// Neighbor mean over fp16 h. One wave per node; 4 edge slots, each slot's
// 16 lanes load a FULL 256B row via uint4 -> 16 rows in flight per wave.
// deg = offs[node+1] - offs[node].
// ---------------------------------------------------------------------------
__global__ void aggregate_h16(const __half* __restrict__ h, const int* __restrict__ offs,
                              const int* __restrict__ csr,
                              __half* __restrict__ agg, int n) {
    const int node = blockIdx.x * 4 + (threadIdx.x >> 6);
    if (node >= n) return;
    const int lane = threadIdx.x & 63;
    const int slot = lane >> 4;          // edge slot (0..3)
    const int c8 = (lane & 15) * 8;      // 8 cols per lane
    const int start = offs[node];
    const int d = offs[node + 1] - start;
    float a[8] = {0.f, 0.f, 0.f, 0.f, 0.f, 0.f, 0.f, 0.f};
    for (int i = slot; i < d; i += 16) {
        #pragma unroll
        for (int u = 0; u < 4; ++u) {
            const int e = i + u * 4;
            if (e < d) {
                const int s = csr[start + e];
                uint4 raw = *(const uint4*)&h[(size_t)s * HIDDEN + c8];
                const __half2* hp = (const __half2*)&raw;
                #pragma unroll
                for (int m = 0; m < 4; ++m) {
                    float2 f = __half22float2(hp[m]);
                    a[2 * m] += f.x;
                    a[2 * m + 1] += f.y;
                }
            }
        }
    }
    #pragma unroll
    for (int k = 0; k < 8; ++k) {
        a[k] += __shfl_xor(a[k], 16, 64);
        a[k] += __shfl_xor(a[k], 32, 64);
    }
    if (slot == 0) {
        const float inv = 1.0f / (float)max(d, 1);
        uint4 raw;
        __half2* op = (__half2*)&raw;
        #pragma unroll
        for (int m = 0; m < 4; ++m)
            op[m] = __floats2half2_rn(a[2 * m] * inv, a[2 * m + 1] * inv);
        *(uint4*)&agg[(size_t)node * HIDDEN + c8] = raw;
    }
}

// ---------------------------------------------------------------------------
extern "C" void kernel_launch(void* const* d_in, const int* in_sizes, int n_in,
                              void* d_out, int out_size, void* d_ws, size_t ws_size,
                              hipStream_t stream) {
    const float* x     = (const float*)d_in[0];
    const float* W_t   = (const float*)d_in[1];
    const float* b_t   = (const float*)d_in[2];
    const float* W_s0  = (const float*)d_in[3];
    const float* b_s0  = (const float*)d_in[4];
    const float* W_n0  = (const float*)d_in[5];
    const float* W_s1  = (const float*)d_in[6];
    const float* b_s1  = (const float*)d_in[7];
    const float* W_n1  = (const float*)d_in[8];
    const float* W_fin = (const float*)d_in[9];
    const int*   src   = (const int*)d_in[10];
    const int*   dst   = (const int*)d_in[11];
    float* out = (float*)d_out;

    const int N = in_sizes[0] / 256;   // 100000
    const int E = in_sizes[10];        // 1600000

    size_t off_b = 0;
    auto carve = [&](size_t bytes) {
        size_t cur = off_b;
        off_b = (off_b + bytes + 255) & ~(size_t)255;
        return cur;
    };
    char* base = (char*)d_ws;
    int* offs   = (int*)(base + carve((size_t)(N + 1) * 4));
    int* bcnt   = (int*)(base + carve(NBUCK_MAX * 4));
    int* boffs  = (int*)(base + carve((NBUCK_MAX + 1) * 4));
    int* cursor = (int*)(base + carve(NBUCK_MAX * 4));
    int* csr    = (int*)(base + carve((size_t)E * 4));
    unsigned long long* pairs = (unsigned long long*)(base + carve((size_t)E * 8));
    __half* wp_t  = (__half*)(base + carve((size_t)65536 * 2));
    __half* wp_l0 = (__half*)(base + carve((size_t)65536 * 2));
    __half* wp_l1 = (__half*)(base + carve((size_t)65536 * 2));
    __half* hA  = (__half*)(base + carve((size_t)N * HIDDEN * 2));
    __half* hB  = (__half*)(base + carve((size_t)N * HIDDEN * 2));
    __half* agp = (__half*)(base + carve((size_t)N * HIDDEN * 2));
    (void)ws_size; (void)n_in; (void)out_size;

    const int nBuck = (N + (1 << BSHIFT) - 1) >> BSHIFT;   // 196

    // --- CSR build (bucketed) ---
    hipLaunchKernelGGL(zero_ints, dim3(1), dim3(256), 0, stream, bcnt, NBUCK_MAX);
    hipLaunchKernelGGL(bucket_hist, dim3((E + 4095) / 4096), dim3(256), 0, stream, dst, bcnt, E);
    hipLaunchKernelGGL(scan_buckets, dim3(1), dim3(256), 0, stream, bcnt, boffs, cursor, nBuck);
    hipLaunchKernelGGL(partition_pairs, dim3((E + 4095) / 4096), dim3(256), 0, stream,
                       src, dst, cursor, pairs, E);
    hipLaunchKernelGGL(place_csr2, dim3(nBuck), dim3(256), 0, stream, pairs, boffs, offs, csr, N, E);

    // --- weight packing (48 tiny blocks) ---
    hipLaunchKernelGGL(pack_weights, dim3(48), dim3(256), 0, stream,
                       W_t, W_s0, W_n0, W_s1, W_n1, wp_t, wp_l0, wp_l1);

    const int gemmGrid = (N + 127) / 128;
    const int xGrid = (N + 63) / 64;
    const int nodeGrid = (N + 3) / 4;

    // h0 = x @ W_t + b_t  (f32 burst DMA, cvt at read)
    hipLaunchKernelGGL(gemm_x32, dim3(xGrid), dim3(256), 0, stream,
                       x, wp_t, b_t, hA, N);
    // layer 0
    hipLaunchKernelGGL(aggregate_h16, dim3(nodeGrid), dim3(256), 0, stream, hA, offs, csr, agp, N);
    hipLaunchKernelGGL((gemm_h16<true, false>), dim3(gemmGrid), dim3(256), 0, stream,
                       hA, agp, wp_l0, b_s0, (const float*)nullptr, (void*)hB, N);
    // layer 1 + fused final projection
    hipLaunchKernelGGL(aggregate_h16, dim3(nodeGrid), dim3(256), 0, stream, hB, offs, csr, agp, N);
    hipLaunchKernelGGL((gemm_h16<true, true>), dim3(gemmGrid), dim3(256), 0, stream,
                       hB, agp, wp_l1, b_s1, W_fin, (void*)out, N);
}

// Round 11
// 287.655 us; speedup vs baseline: 1.4463x; 1.0684x over previous
//
#include <hip/hip_runtime.h>
#include <hip/hip_fp16.h>

#define HIDDEN 128
#define BSHIFT 9                  // 512 nodes per bucket
#define NBUCK_MAX 256

using f32x4 = __attribute__((ext_vector_type(4))) float;
using f16x8 = __attribute__((ext_vector_type(8))) _Float16;

__device__ __forceinline__ void gload16(const void* g, void* l) {
    __builtin_amdgcn_global_load_lds((const __attribute__((address_space(1))) void*)g,
                                     (__attribute__((address_space(3))) void*)l,
                                     16, 0, 0);
}

// ---------------------------------------------------------------------------
// CSR build (bucketed, no per-node global atomics)
// ---------------------------------------------------------------------------
__global__ void zero_ints(int* __restrict__ a, int n) {
    int i = blockIdx.x * 256 + threadIdx.x;
    if (i < n) a[i] = 0;
}

__launch_bounds__(256)
__global__ void bucket_hist(const int* __restrict__ dst, int* __restrict__ bcnt, int e) {
    __shared__ int c[NBUCK_MAX];
    const int t = threadIdx.x;
    c[t] = 0;
    __syncthreads();
    const int tile0 = blockIdx.x * 4096;
    const int end = min(e, tile0 + 4096);
    for (int i = tile0 + t; i < end; i += 256)
        atomicAdd(&c[dst[i] >> BSHIFT], 1);
    __syncthreads();
    if (c[t]) atomicAdd(&bcnt[t], c[t]);
}

__global__ void scan_buckets(const int* __restrict__ bcnt, int* __restrict__ boffs,
                             int* __restrict__ cursor, int nb) {
    __shared__ int sd[256];
    const int t = threadIdx.x;
    int v = (t < nb) ? bcnt[t] : 0;
    sd[t] = v;
    __syncthreads();
    for (int o = 1; o < 256; o <<= 1) {
        int add = (t >= o) ? sd[t - o] : 0;
        __syncthreads();
        sd[t] += add;
        __syncthreads();
    }
    const int ex = sd[t] - v;
    if (t < nb) { boffs[t] = ex; cursor[t] = ex; }
    if (t == nb - 1) boffs[nb] = ex + v;
}

__launch_bounds__(256)
__global__ void partition_pairs(const int* __restrict__ src, const int* __restrict__ dst,
                                int* __restrict__ cursor,
                                unsigned long long* __restrict__ pairs, int e) {
    __shared__ int cnt[NBUCK_MAX];
    __shared__ int base[NBUCK_MAX];
    const int t = threadIdx.x;
    const int tile0 = blockIdx.x * 4096;
    cnt[t] = 0;
    __syncthreads();
    int s[16], d[16], b[16];
    #pragma unroll
    for (int j = 0; j < 16; ++j) {
        const int i = tile0 + j * 256 + t;
        if (i < e) {
            d[j] = dst[i];
            s[j] = src[i];
            b[j] = d[j] >> BSHIFT;
            atomicAdd(&cnt[b[j]], 1);
        } else {
            b[j] = -1;
        }
    }
    __syncthreads();
    const int c = cnt[t];
    base[t] = c ? atomicAdd(&cursor[t], c) : 0;
    __syncthreads();
    cnt[t] = 0;
    __syncthreads();
    #pragma unroll
    for (int j = 0; j < 16; ++j) {
        if (b[j] >= 0) {
            const int r = atomicAdd(&cnt[b[j]], 1);
            pairs[(size_t)base[b[j]] + r] =
                ((unsigned long long)(unsigned)d[j] << 32) | (unsigned)s[j];
        }
    }
}

__launch_bounds__(256)
__global__ void place_csr2(const unsigned long long* __restrict__ pairs,
                           const int* __restrict__ boffs,
                           int* __restrict__ offs, int* __restrict__ csr,
                           int n, int e) {
    __shared__ int cnt[1 << BSHIFT];
    __shared__ int sc[256];
    const int b = blockIdx.x;
    const int t = threadIdx.x;
    const int node0 = b << BSHIFT;
    const int nn = min(1 << BSHIFT, n - node0);
    cnt[t] = 0;
    cnt[t + 256] = 0;
    __syncthreads();
    const int beg = boffs[b], end = boffs[b + 1];
    for (int i = beg + t; i < end; i += 256)
        atomicAdd(&cnt[(int)(pairs[i] >> 32) - node0], 1);
    __syncthreads();
    const int a0 = cnt[2 * t], a1 = cnt[2 * t + 1];
    const int s = a0 + a1;
    sc[t] = s;
    __syncthreads();
    for (int o = 1; o < 256; o <<= 1) {
        int add = (t >= o) ? sc[t - o] : 0;
        __syncthreads();
        sc[t] += add;
        __syncthreads();
    }
    const int g0 = beg + sc[t] - s;
    const int g1 = g0 + a0;
    if (2 * t < nn)     offs[node0 + 2 * t] = g0;
    if (2 * t + 1 < nn) offs[node0 + 2 * t + 1] = g1;
    __syncthreads();
    cnt[2 * t] = g0;
    cnt[2 * t + 1] = g1;
    if (node0 + nn == n && t == 0) offs[n] = e;   // sentinel
    __syncthreads();
    for (int i = beg + t; i < end; i += 256) {
        const unsigned long long pr = pairs[i];
        const int dd = (int)(pr >> 32) - node0;
        const int ss = (int)(unsigned)pr;
        const int p = atomicAdd(&cnt[dd], 1);
        csr[p] = ss;
    }
}

// ---------------------------------------------------------------------------
// Pack weights into MFMA-fragment-ordered f16 planes (Wh + Wls*32).
// ---------------------------------------------------------------------------
__global__ void pack_weights(const float* __restrict__ W_t, const float* __restrict__ Ws0,
                             const float* __restrict__ Wn0, const float* __restrict__ Ws1,
                             const float* __restrict__ Wn1,
                             __half* p_t, __half* p_l0, __half* p_l1) {
    const int bid = blockIdx.x;
    const float* W; __half* out; int b0; int S0;
    if (bid < 16)      { W = W_t; out = p_t;  b0 = 0;  S0 = 0; }
    else if (bid < 24) { W = Ws0; out = p_l0; b0 = 16; S0 = 0; }
    else if (bid < 32) { W = Wn0; out = p_l0; b0 = 24; S0 = 4; }
    else if (bid < 40) { W = Ws1; out = p_l1; b0 = 32; S0 = 0; }
    else               { W = Wn1; out = p_l1; b0 = 40; S0 = 4; }
    const int idx = (bid - b0) * 256 + threadIdx.x;
    const int step = idx >> 9;
    const int r = idx & 511;
    const int l = r & 63;
    const int col = (r >> 6) * 16 + (l & 15);
    const int k0 = step * 32 + ((l >> 4) << 3);
    const size_t o = (size_t)(S0 + step) * 4096 + (size_t)r * 8;
    #pragma unroll
    for (int j = 0; j < 8; ++j) {
        float f = W[(k0 + j) * HIDDEN + col];
        __half h = __float2half_rn(f);
        out[o + j] = h;
        out[32768 + o + j] = __float2half_rn((f - __half2float(h)) * 32.0f);
    }
}

// ---------------------------------------------------------------------------
// Layer GEMM, high-occupancy: 64-row tile (32 KB LDS -> 4-5 blocks/CU).
// 4 waves col-split: wave w owns cols [w*32, w*32+32). Single DMA burst +
// ONE barrier + barrier-free K-loop. acc += A*Wh + (A*2^-5)*Wls.
// ---------------------------------------------------------------------------
template <bool RELU, bool FINAL>
__launch_bounds__(256, 4)
__global__ void gemm64(const __half* __restrict__ A0, const __half* __restrict__ A1,
                       const __half* __restrict__ Wp,
                       const float* __restrict__ bias,
                       const float* __restrict__ wfin,
                       void* __restrict__ outv, int nrows) {
    __shared__ __align__(16) __half As[8][4][64][8];   // [step][rt][lane][8] = 32 KB
    __shared__ float red[FINAL ? 64 : 1][4];

    const int t = threadIdx.x;
    const int lane = t & 63;
    const int w = t >> 6;
    const int blockRow0 = blockIdx.x * 64;

    // burst-stage: wave w stages rt = w for all 8 steps (8 DMAs in flight)
    {
        const int row = min(blockRow0 + w * 16 + (lane & 15), nrows - 1);
        const int koff = (lane >> 4) << 3;
        #pragma unroll
        for (int step = 0; step < 8; ++step) {
            const __half* src = ((step < 4) ? A0 : A1) + (size_t)row * HIDDEN + (step & 3) * 32 + koff;
            gload16(src, &As[step][w][0][0]);
        }
    }
    __syncthreads();   // single drain; LDS read-only afterwards

    f32x4 acc[4][2];
    #pragma unroll
    for (int i = 0; i < 4; ++i)
        #pragma unroll
        for (int j = 0; j < 2; ++j) acc[i][j] = (f32x4){0.f, 0.f, 0.f, 0.f};

    const _Float16 S = (_Float16)0.03125f;   // 2^-5

    #pragma unroll
    for (int step = 0; step < 8; ++step) {
        const __half* wb = Wp + (size_t)step * 4096 + (w * 2) * 512 + lane * 8;
        f16x8 wh[2], wl[2];
        #pragma unroll
        for (int c2 = 0; c2 < 2; ++c2) {
            wh[c2] = *(const f16x8*)(wb + c2 * 512);
            wl[c2] = *(const f16x8*)(wb + 32768 + c2 * 512);
        }
        f16x8 a[4], asr[4];
        #pragma unroll
        for (int r4 = 0; r4 < 4; ++r4) {
            a[r4] = *(const f16x8*)&As[step][r4][lane][0];
            asr[r4] = a[r4] * S;
        }
        #pragma unroll
        for (int r4 = 0; r4 < 4; ++r4)
            #pragma unroll
            for (int c2 = 0; c2 < 2; ++c2) {
                acc[r4][c2] = __builtin_amdgcn_mfma_f32_16x16x32_f16(a[r4], wh[c2], acc[r4][c2], 0, 0, 0);
                acc[r4][c2] = __builtin_amdgcn_mfma_f32_16x16x32_f16(asr[r4], wl[c2], acc[r4][c2], 0, 0, 0);
            }
    }

    if constexpr (FINAL) {
        // fused out = relu(acc + bias) @ wfin; cross-wave col reduction via LDS
        float wf[2], bc[2];
        #pragma unroll
        for (int c2 = 0; c2 < 2; ++c2) {
            const int col = w * 32 + c2 * 16 + (lane & 15);
            wf[c2] = wfin[col];
            bc[c2] = bias[col];
        }
        float part[4][4];
        #pragma unroll
        for (int r4 = 0; r4 < 4; ++r4)
            #pragma unroll
            for (int j = 0; j < 4; ++j) {
                float s = 0.f;
                #pragma unroll
                for (int c2 = 0; c2 < 2; ++c2) {
                    float v = acc[r4][c2][j] + bc[c2];
                    if (RELU) v = fmaxf(v, 0.f);
                    s = fmaf(v, wf[c2], s);
                }
                part[r4][j] = s;
            }
        #pragma unroll
        for (int o = 1; o < 16; o <<= 1)
            #pragma unroll
            for (int r4 = 0; r4 < 4; ++r4)
                #pragma unroll
                for (int j = 0; j < 4; ++j)
                    part[r4][j] += __shfl_xor(part[r4][j], o, 64);
        if ((lane & 15) == 0) {
            #pragma unroll
            for (int r4 = 0; r4 < 4; ++r4)
                #pragma unroll
                for (int j = 0; j < 4; ++j)
                    red[r4 * 16 + ((lane >> 4) << 2) + j][w] = part[r4][j];
        }
        __syncthreads();
        if (t < 64) {
            const int r = blockRow0 + t;
            if (r < nrows)
                ((float*)outv)[r] = red[t][0] + red[t][1] + red[t][2] + red[t][3];
        }
    } else {
        __half* out = (__half*)outv;
        #pragma unroll
        for (int c2 = 0; c2 < 2; ++c2) {
            const int col = w * 32 + c2 * 16 + (lane & 15);
            const float bc = bias[col];
            #pragma unroll
            for (int r4 = 0; r4 < 4; ++r4) {
                const int r0 = blockRow0 + r4 * 16 + ((lane >> 4) << 2);
                #pragma unroll
                for (int j = 0; j < 4; ++j) {
                    const int r = r0 + j;
                    if (r < nrows) {
                        float v = acc[r4][c2][j] + bc;
                        if (RELU) v = fmaxf(v, 0.f);
                        out[(size_t)r * HIDDEN + col] = __float2half(v);
                    }
                }
            }
        }
    }
}

// ---------------------------------------------------------------------------
// Transform GEMM, high-occupancy: 32-row f32 tile (32 KB LDS -> 4-5 blocks/CU),
// 4 waves col-split, single DMA burst + ONE barrier; f32->f16 cvt at read.
// ---------------------------------------------------------------------------
__launch_bounds__(256, 4)
__global__ void gemm_x32v(const float* __restrict__ X, const __half* __restrict__ Wp,
                          const float* __restrict__ bias,
                          __half* __restrict__ outp, int nrows) {
    __shared__ __align__(16) float Xs[8][2][2][64][4];   // [step][rt][half][lane][4] = 32 KB

    const int t = threadIdx.x;
    const int lane = t & 63;
    const int w = t >> 6;
    const int blockRow0 = blockIdx.x * 32;

    // burst-stage: wave w stages rt = w>>1, half = w&1 for all 8 steps (8 DMAs)
    {
        const int rt = w >> 1, hf = w & 1;
        const int row = min(blockRow0 + rt * 16 + (lane & 15), nrows - 1);
        const int k0 = ((lane >> 4) << 3) + hf * 4;
        #pragma unroll
        for (int step = 0; step < 8; ++step) {
            const float* src = X + (size_t)row * 256 + step * 32 + k0;
            gload16(src, &Xs[step][rt][hf][0][0]);
        }
    }
    __syncthreads();   // single drain

    f32x4 acc[2][2];
    #pragma unroll
    for (int i = 0; i < 2; ++i)
        #pragma unroll
        for (int j = 0; j < 2; ++j) acc[i][j] = (f32x4){0.f, 0.f, 0.f, 0.f};

    const _Float16 S = (_Float16)0.03125f;   // 2^-5

    #pragma unroll
    for (int step = 0; step < 8; ++step) {
        const __half* wb = Wp + (size_t)step * 4096 + (w * 2) * 512 + lane * 8;
        f16x8 wh[2], wl[2];
        #pragma unroll
        for (int c2 = 0; c2 < 2; ++c2) {
            wh[c2] = *(const f16x8*)(wb + c2 * 512);
            wl[c2] = *(const f16x8*)(wb + 32768 + c2 * 512);
        }
        f16x8 a[2], asr[2];
        #pragma unroll
        for (int r2 = 0; r2 < 2; ++r2) {
            f32x4 x0 = *(const f32x4*)&Xs[step][r2][0][lane][0];
            f32x4 x1 = *(const f32x4*)&Xs[step][r2][1][lane][0];
            f16x8 hh;
            #pragma unroll
            for (int j = 0; j < 4; ++j) hh[j] = (_Float16)x0[j];
            #pragma unroll
            for (int j = 0; j < 4; ++j) hh[4 + j] = (_Float16)x1[j];
            a[r2] = hh;
            asr[r2] = hh * S;
        }
        #pragma unroll
        for (int r2 = 0; r2 < 2; ++r2)
            #pragma unroll
            for (int c2 = 0; c2 < 2; ++c2) {
                acc[r2][c2] = __builtin_amdgcn_mfma_f32_16x16x32_f16(a[r2], wh[c2], acc[r2][c2], 0, 0, 0);
                acc[r2][c2] = __builtin_amdgcn_mfma_f32_16x16x32_f16(asr[r2], wl[c2], acc[r2][c2], 0, 0, 0);
            }
    }

    // epilogue: bias, fp16 h store
    #pragma unroll
    for (int c2 = 0; c2 < 2; ++c2) {
        const int col = w * 32 + c2 * 16 + (lane & 15);
        const float bc = bias[col];
        #pragma unroll
        for (int r2 = 0; r2 < 2; ++r2) {
            const int r0 = blockRow0 + r2 * 16 + ((lane >> 4) << 2);
            #pragma unroll
            for (int j = 0; j < 4; ++j) {
                const int r = r0 + j;
                if (r < nrows)
                    outp[(size_t)r * HIDDEN + col] = __float2half(acc[r2][c2][j] + bc);
            }
        }
    }
}

// ---------------------------------------------------------------------------
// Neighbor mean over fp16 h. One wave per node; 4 edge slots, full-row uint4
// loads; deg = offs[node+1] - offs[node].
// ---------------------------------------------------------------------------
__global__ void aggregate_h16(const __half* __restrict__ h, const int* __restrict__ offs,
                              const int* __restrict__ csr,
                              __half* __restrict__ agg, int n) {
    const int node = blockIdx.x * 4 + (threadIdx.x >> 6);
    if (node >= n) return;
    const int lane = threadIdx.x & 63;
    const int slot = lane >> 4;          // edge slot (0..3)
    const int c8 = (lane & 15) * 8;      // 8 cols per lane
    const int start = offs[node];
    const int d = offs[node + 1] - start;
    float a[8] = {0.f, 0.f, 0.f, 0.f, 0.f, 0.f, 0.f, 0.f};
    for (int i = slot; i < d; i += 16) {
        #pragma unroll
        for (int u = 0; u < 4; ++u) {
            const int e = i + u * 4;
            if (e < d) {
                const int s = csr[start + e];
                uint4 raw = *(const uint4*)&h[(size_t)s * HIDDEN + c8];
                const __half2* hp = (const __half2*)&raw;
                #pragma unroll
                for (int m = 0; m < 4; ++m) {
                    float2 f = __half22float2(hp[m]);
                    a[2 * m] += f.x;
                    a[2 * m + 1] += f.y;
                }
            }
        }
    }
    #pragma unroll
    for (int k = 0; k < 8; ++k) {
        a[k] += __shfl_xor(a[k], 16, 64);
        a[k] += __shfl_xor(a[k], 32, 64);
    }
    if (slot == 0) {
        const float inv = 1.0f / (float)max(d, 1);
        uint4 raw;
        __half2* op = (__half2*)&raw;
        #pragma unroll
        for (int m = 0; m < 4; ++m)
            op[m] = __floats2half2_rn(a[2 * m] * inv, a[2 * m + 1] * inv);
        *(uint4*)&agg[(size_t)node * HIDDEN + c8] = raw;
    }
}

// ---------------------------------------------------------------------------
extern "C" void kernel_launch(void* const* d_in, const int* in_sizes, int n_in,
                              void* d_out, int out_size, void* d_ws, size_t ws_size,
                              hipStream_t stream) {
    const float* x     = (const float*)d_in[0];
    const float* W_t   = (const float*)d_in[1];
    const float* b_t   = (const float*)d_in[2];
    const float* W_s0  = (const float*)d_in[3];
    const float* b_s0  = (const float*)d_in[4];
    const float* W_n0  = (const float*)d_in[5];
    const float* W_s1  = (const float*)d_in[6];
    const float* b_s1  = (const float*)d_in[7];
    const float* W_n1  = (const float*)d_in[8];
    const float* W_fin = (const float*)d_in[9];
    const int*   src   = (const int*)d_in[10];
    const int*   dst   = (const int*)d_in[11];
    float* out = (float*)d_out;

    const int N = in_sizes[0] / 256;   // 100000
    const int E = in_sizes[10];        // 1600000

    size_t off_b = 0;
    auto carve = [&](size_t bytes) {
        size_t cur = off_b;
        off_b = (off_b + bytes + 255) & ~(size_t)255;
        return cur;
    };
    char* base = (char*)d_ws;
    int* offs   = (int*)(base + carve((size_t)(N + 1) * 4));
    int* bcnt   = (int*)(base + carve(NBUCK_MAX * 4));
    int* boffs  = (int*)(base + carve((NBUCK_MAX + 1) * 4));
    int* cursor = (int*)(base + carve(NBUCK_MAX * 4));
    int* csr    = (int*)(base + carve((size_t)E * 4));
    unsigned long long* pairs = (unsigned long long*)(base + carve((size_t)E * 8));
    __half* wp_t  = (__half*)(base + carve((size_t)65536 * 2));
    __half* wp_l0 = (__half*)(base + carve((size_t)65536 * 2));
    __half* wp_l1 = (__half*)(base + carve((size_t)65536 * 2));
    __half* hA  = (__half*)(base + carve((size_t)N * HIDDEN * 2));
    __half* hB  = (__half*)(base + carve((size_t)N * HIDDEN * 2));
    __half* agp = (__half*)(base + carve((size_t)N * HIDDEN * 2));
    (void)ws_size; (void)n_in; (void)out_size;

    const int nBuck = (N + (1 << BSHIFT) - 1) >> BSHIFT;   // 196

    // --- CSR build (bucketed) ---
    hipLaunchKernelGGL(zero_ints, dim3(1), dim3(256), 0, stream, bcnt, NBUCK_MAX);
    hipLaunchKernelGGL(bucket_hist, dim3((E + 4095) / 4096), dim3(256), 0, stream, dst, bcnt, E);
    hipLaunchKernelGGL(scan_buckets, dim3(1), dim3(256), 0, stream, bcnt, boffs, cursor, nBuck);
    hipLaunchKernelGGL(partition_pairs, dim3((E + 4095) / 4096), dim3(256), 0, stream,
                       src, dst, cursor, pairs, E);
    hipLaunchKernelGGL(place_csr2, dim3(nBuck), dim3(256), 0, stream, pairs, boffs, offs, csr, N, E);

    // --- weight packing (48 tiny blocks) ---
    hipLaunchKernelGGL(pack_weights, dim3(48), dim3(256), 0, stream,
                       W_t, W_s0, W_n0, W_s1, W_n1, wp_t, wp_l0, wp_l1);

    const int g64 = (N + 63) / 64;     // 1563
    const int g32 = (N + 31) / 32;     // 3125
    const int nodeGrid = (N + 3) / 4;

    // h0 = x @ W_t + b_t  (f32 burst DMA, cvt at read, 4-5 blocks/CU)
    hipLaunchKernelGGL(gemm_x32v, dim3(g32), dim3(256), 0, stream,
                       x, wp_t, b_t, hA, N);
    // layer 0
    hipLaunchKernelGGL(aggregate_h16, dim3(nodeGrid), dim3(256), 0, stream, hA, offs, csr, agp, N);
    hipLaunchKernelGGL((gemm64<true, false>), dim3(g64), dim3(256), 0, stream,
                       hA, agp, wp_l0, b_s0, (const float*)nullptr, (void*)hB, N);
    // layer 1 + fused final projection
    hipLaunchKernelGGL(aggregate_h16, dim3(nodeGrid), dim3(256), 0, stream, hB, offs, csr, agp, N);
    hipLaunchKernelGGL((gemm64<true, true>), dim3(g64), dim3(256), 0, stream,
                       hB, agp, wp_l1, b_s1, W_fin, (void*)out, N);
}